// Round 1
// baseline (326.924 us; speedup 1.0000x reference)
//
#include <hip/hip_runtime.h>
#include <cmath>

// Problem constants (fixed by reference): B=8, Cin=16, H=W=128, Cout=64, E=16, K=2
#define NTHR 256

// LDS layout (floats):
//   xt   : 16 ci * 4 rows * 132 cols       = 8448
//   wt   : 144 kk * 72 (64 couts + pad)    = 10368
//   outt : 256 px * 65 (64 couts + pad)    = 16640
//   list_w  : 512 floats
//   list_pix: 512 ints
//   cnt[16], basep[16]
// total = 36512 * 4 B = 146048 B  (1 block/CU on 160 KiB LDS)

__global__ __launch_bounds__(256) void moe_sparse_conv_kernel(
    const float* __restrict__ x,      // [8][16][128][128]
    const float* __restrict__ gw,     // [16][16]
    const float* __restrict__ gb,     // [16]
    const float* __restrict__ ew,     // [16][64][16][3][3]
    const float* __restrict__ eb,     // [16][64]
    float* __restrict__ out,          // [8][64][128][128]
    float* __restrict__ logits_out)   // [8][16][128][128]
{
    extern __shared__ float lds[];
    float* xt      = lds;                       // 8448
    float* wt      = xt + 8448;                 // 10368
    float* outt    = wt + 10368;                // 16640
    float* list_w  = outt + 16640;              // 512
    int*   list_pix= (int*)(list_w + 512);      // 512
    int*   cnt     = list_pix + 512;            // 16
    int*   basep   = cnt + 16;                  // 16

    const int tid  = threadIdx.x;
    const int b    = blockIdx.x >> 6;           // 8 batches
    const int row0 = (blockIdx.x & 63) << 1;    // 64 row-pairs

    // ---- stage x tile (rows row0-1..row0+2, cols -1..130, zero padded) ----
    for (int i = tid; i < 8448; i += NTHR) {
        int ci  = i / 528;            // 528 = 4*132
        int rem = i - ci * 528;
        int r   = rem / 132;
        int cc  = rem - r * 132;
        int gr  = row0 - 1 + r;
        int gc  = cc - 1;
        float v = 0.f;
        if (gr >= 0 && gr < 128 && gc >= 0 && gc < 128)
            v = x[((b * 16 + ci) * 128 + gr) * 128 + gc];
        xt[i] = v;
    }
    for (int i = tid; i < 16640; i += NTHR) outt[i] = 0.f;
    if (tid < 16) cnt[tid] = 0;
    __syncthreads();

    // ---- gate: one thread per pixel (256 pixels) ----
    const int pcol = tid & 127;
    const int prow = tid >> 7;
    float l[16];
    {
        float xv[16];
        #pragma unroll
        for (int ci = 0; ci < 16; ++ci)
            xv[ci] = xt[ci * 528 + (prow + 1) * 132 + (pcol + 1)];
        #pragma unroll
        for (int o = 0; o < 16; ++o) {
            float acc = gb[o];
            #pragma unroll
            for (int i = 0; i < 16; ++i) acc += gw[o * 16 + i] * xv[i];
            l[o] = acc;
        }
    }
    {   // write logits output (coalesced: consecutive tid -> consecutive col)
        int rbase = (b * 16 * 128 + (row0 + prow)) * 128 + pcol;
        #pragma unroll
        for (int o = 0; o < 16; ++o)
            logits_out[rbase + o * 16384] = l[o];
    }
    // softmax-monotone top-2 (strict > keeps lowest index on ties, matching
    // jax.lax.top_k stable descending order)
    float m = l[0];
    #pragma unroll
    for (int o = 1; o < 16; ++o) m = fmaxf(m, l[o]);
    float p[16];
    #pragma unroll
    for (int o = 0; o < 16; ++o) p[o] = expf(l[o] - m);
    float p0 = p[0], p1 = -1.f;
    int   i0 = 0,    i1 = 0;
    #pragma unroll
    for (int o = 1; o < 16; ++o) {
        float pv = p[o];
        if (pv > p0)      { p1 = p0; i1 = i0; p0 = pv; i0 = o; }
        else if (pv > p1) { p1 = pv; i1 = o; }
    }
    const float wsum = p0 + p1;
    const float w0 = p0 / wsum, w1 = p1 / wsum;

    atomicAdd(&cnt[i0], 1);
    atomicAdd(&cnt[i1], 1);
    __syncthreads();
    if (tid == 0) {
        int run = 0;
        for (int e = 0; e < 16; ++e) { basep[e] = run; run += cnt[e]; cnt[e] = 0; }
    }
    __syncthreads();
    {
        int pos = atomicAdd(&cnt[i0], 1);
        list_pix[basep[i0] + pos] = tid;  list_w[basep[i0] + pos] = w0;
        pos = atomicAdd(&cnt[i1], 1);
        list_pix[basep[i1] + pos] = tid;  list_w[basep[i1] + pos] = w1;
    }
    __syncthreads();

    // ---- expert loop: stage weights once, process that expert's pixel list ----
    const int cg    = tid & 15;   // cout group: couts cg*4 .. cg*4+3
    const int pslot = tid >> 4;   // 16 pixel slots

    for (int e = 0; e < 16; ++e) {
        // stage weights: global read perfectly coalesced (i consecutive),
        // LDS write stride 72 floats -> <=4-way bank conflict (acceptable)
        for (int i = tid; i < 9216; i += NTHR) {
            int cl = i / 144;
            int kk = i - cl * 144;
            wt[kk * 72 + cl] = ew[e * 9216 + i];
        }
        __syncthreads();

        const int n  = cnt[e];
        const int nb = basep[e];
        for (int idx0 = pslot * 2; idx0 < n; idx0 += 32) {
            const int idx1 = idx0 + 1;
            int   pA = list_pix[nb + idx0];
            float wA = list_w[nb + idx0];
            int   pB = pA;
            float wB = 0.f;
            if (idx1 < n) { pB = list_pix[nb + idx1]; wB = list_w[nb + idx1]; }
            const int cA = pA & 127, rA = pA >> 7;
            const int cB = pB & 127, rB = pB >> 7;

            float a0=0.f,a1=0.f,a2=0.f,a3=0.f;
            float b0=0.f,b1=0.f,b2=0.f,b3=0.f;
            for (int ci = 0; ci < 16; ++ci) {
                const int xbA = ci * 528 + rA * 132 + cA;
                const int xbB = ci * 528 + rB * 132 + cB;
                const int wb  = ci * 9 * 72 + cg * 4;
                #pragma unroll
                for (int ky = 0; ky < 3; ++ky) {
                    #pragma unroll
                    for (int kx = 0; kx < 3; ++kx) {
                        const float4 wv = *(const float4*)&wt[wb + (ky * 3 + kx) * 72];
                        const float xa = xt[xbA + ky * 132 + kx];
                        const float xb = xt[xbB + ky * 132 + kx];
                        a0 += wv.x * xa; a1 += wv.y * xa; a2 += wv.z * xa; a3 += wv.w * xa;
                        b0 += wv.x * xb; b1 += wv.y * xb; b2 += wv.z * xb; b3 += wv.w * xb;
                    }
                }
            }
            const float4 bias = *(const float4*)&eb[e * 64 + cg * 4];
            const int oA = pA * 65 + cg * 4;
            outt[oA + 0] += wA * (a0 + bias.x);
            outt[oA + 1] += wA * (a1 + bias.y);
            outt[oA + 2] += wA * (a2 + bias.z);
            outt[oA + 3] += wA * (a3 + bias.w);
            if (wB != 0.f) {
                const int oB = pB * 65 + cg * 4;
                outt[oB + 0] += wB * (b0 + bias.x);
                outt[oB + 1] += wB * (b1 + bias.y);
                outt[oB + 2] += wB * (b2 + bias.z);
                outt[oB + 3] += wB * (b3 + bias.w);
            }
        }
        __syncthreads();
    }

    // ---- writeout: LDS conflict-free (stride 65), global coalesced ----
    for (int i = tid; i < 16384; i += NTHR) {
        const int c   = i >> 8;
        const int pix = i & 255;
        const int pr  = pix >> 7, pc = pix & 127;
        out[((b * 64 + c) * 128 + row0 + pr) * 128 + pc] = outt[pix * 65 + c];
    }
}

extern "C" void kernel_launch(void* const* d_in, const int* in_sizes, int n_in,
                              void* d_out, int out_size, void* d_ws, size_t ws_size,
                              hipStream_t stream) {
    const float* x  = (const float*)d_in[0];
    const float* gw = (const float*)d_in[1];
    const float* gb = (const float*)d_in[2];
    const float* ew = (const float*)d_in[3];
    const float* eb = (const float*)d_in[4];
    float* out        = (float*)d_out;
    float* logits_out = out + 8 * 64 * 128 * 128;   // second tuple element

    const size_t smem = 36512 * sizeof(float);      // 146048 B
    // Defensive: allow >64 KiB dynamic LDS (no-op / ignored failure on ROCm)
    (void)hipFuncSetAttribute((const void*)moe_sparse_conv_kernel,
                              hipFuncAttributeMaxDynamicSharedMemorySize,
                              (int)smem);
    dim3 grid(512), block(NTHR);
    moe_sparse_conv_kernel<<<grid, block, smem, stream>>>(x, gw, gb, ew, eb, out, logits_out);
}

// Round 3
// 276.233 us; speedup vs baseline: 1.1835x; 1.1835x over previous
//
#include <hip/hip_runtime.h>
#include <cmath>

// B=8, Cin=16, H=W=128, Cout=64, E=16, K=2
#define NTHR 512

typedef __attribute__((ext_vector_type(8))) short bf16x8;   // MFMA A/B frag (4 VGPRs)
typedef __attribute__((ext_vector_type(4))) float f32x4;    // MFMA C/D frag

// LDS layout (bytes), total 129664 (no aliasing anywhere):
//   A    : [0, 43008)        im2col bf16 [128 px][336 B]  (k 0..143 data, 144..167 zero)
//   outt : [43008, 76288)    fp32 [128 px][65]
//   xt   : [76288, 101632)   fp32 [16 ci][3 r][132 c]
//   Bt   : [101632, 123136)  bf16 [64 cout][336 B]
//   list_pix int[256], list_w float[256], cnt int[16], basep int[16],
//   emask u64[16][2], ebs float[1024]
#define OFF_A     0
#define OFF_OUTT  43008
#define OFF_XT    76288
#define OFF_BT    101632
#define OFF_LPIX  123136
#define OFF_LW    124160
#define OFF_CNT   125184
#define OFF_BASE  125248
#define OFF_MASK  125312
#define OFF_EBS   125568
#define SMEM_B    129664

static __device__ __forceinline__ unsigned short f2bf(float f) {
    union { float f; unsigned int u; } v; v.f = f;
    unsigned int r = v.u + 0x7FFFu + ((v.u >> 16) & 1u);   // round-to-nearest-even
    return (unsigned short)(r >> 16);
}

__global__ __launch_bounds__(512) void moe_mfma3_kernel(
    const float* __restrict__ x,      // [8][16][128][128]
    const float* __restrict__ gw,     // [16][16]
    const float* __restrict__ gb,     // [16]
    const float* __restrict__ ew,     // [16][64][16][3][3]
    const float* __restrict__ eb,     // [16][64]
    float* __restrict__ out,          // [8][64][128][128]
    float* __restrict__ logits_out)   // [8][16][128][128]
{
    extern __shared__ char lds[];
    char*  Ab       = lds + OFF_A;
    float* outt     = (float*)(lds + OFF_OUTT);
    float* xt       = (float*)(lds + OFF_XT);
    char*  Btb      = lds + OFF_BT;
    int*   list_pix = (int*)(lds + OFF_LPIX);
    float* list_w   = (float*)(lds + OFF_LW);
    int*   cnt      = (int*)(lds + OFF_CNT);
    int*   basep    = (int*)(lds + OFF_BASE);
    unsigned long long* emask = (unsigned long long*)(lds + OFF_MASK);  // [e*2 + half]
    float* ebs      = (float*)(lds + OFF_EBS);

    const int tid = threadIdx.x;
    const int b   = blockIdx.x >> 7;      // 8 batches
    const int row = blockIdx.x & 127;     // 128 rows

    // ---- phase 1: stage xt, zero outt/masks, stage bias ----
    for (int i = tid; i < 6336; i += NTHR) {
        int ci  = i / 396;
        int rem = i - ci * 396;
        int r   = rem / 132;
        int cc  = rem - r * 132;
        int gr = row - 1 + r, gc = cc - 1;
        float v = 0.f;
        if (gr >= 0 && gr < 128 && gc >= 0 && gc < 128)
            v = x[((b * 16 + ci) * 128 + gr) * 128 + gc];
        xt[i] = v;
    }
    for (int i = tid; i < 8320; i += NTHR) outt[i] = 0.f;
    for (int i = tid; i < 1024; i += NTHR) ebs[i] = eb[i];
    if (tid < 32) emask[tid] = 0ull;
    __syncthreads();

    // ---- phase 2: gate (fp32, exact), threads 0..127 = pixels ----
    int i0 = 0, i1 = 0; float w0 = 0.f, w1 = 0.f;
    if (tid < 128) {
        float xv[16];
        #pragma unroll
        for (int ci = 0; ci < 16; ++ci) xv[ci] = xt[ci * 396 + 132 + 1 + tid];
        float l[16];
        #pragma unroll
        for (int o = 0; o < 16; ++o) {
            float acc = gb[o];
            #pragma unroll
            for (int i = 0; i < 16; ++i) acc += gw[o * 16 + i] * xv[i];
            l[o] = acc;
        }
        const int rbase = ((b * 16) * 128 + row) * 128 + tid;
        #pragma unroll
        for (int o = 0; o < 16; ++o) logits_out[rbase + o * 16384] = l[o];

        float m = l[0];
        #pragma unroll
        for (int o = 1; o < 16; ++o) m = fmaxf(m, l[o]);
        float p0 = expf(l[0] - m), p1 = -1.f;
        #pragma unroll
        for (int o = 1; o < 16; ++o) {
            float pv = expf(l[o] - m);
            if (pv > p0)      { p1 = p0; i1 = i0; p0 = pv; i0 = o; }
            else if (pv > p1) { p1 = pv; i1 = o; }
        }
        const float ws = p0 + p1;
        w0 = p0 / ws; w1 = p1 / ws;
        const unsigned long long bit = 1ull << (tid & 63);
        const int half = tid >> 6;
        atomicOr(&emask[i0 * 2 + half], bit);
        atomicOr(&emask[i1 * 2 + half], bit);
    }
    __syncthreads();

    // ---- phase 3: counts + bases (deterministic, from masks) ----
    if (tid == 0) {
        int run = 0;
        for (int e = 0; e < 16; ++e) {
            int c = __popcll(emask[e * 2]) + __popcll(emask[e * 2 + 1]);
            basep[e] = run; cnt[e] = c; run += c;
        }
    }
    __syncthreads();

    // ---- phase 4: deterministic list fill (rank = popcount below my bit) + A-build ----
    if (tid < 128) {
        #pragma unroll
        for (int s = 0; s < 2; ++s) {
            const int   e  = s ? i1 : i0;
            const float wv = s ? w1 : w0;
            const unsigned long long lo = emask[e * 2], hi = emask[e * 2 + 1];
            int pos;
            if (tid < 64) pos = __popcll(lo & ((1ull << tid) - 1ull));
            else          pos = __popcll(lo) + __popcll(hi & ((1ull << (tid - 64)) - 1ull));
            const int slot = basep[e] + pos;
            list_pix[slot] = tid;
            list_w[slot]   = wv;
        }
    }
    // im2col A (bf16): A[px][k], k = ci*9+ky*3+kx  (reads xt only)
    for (int i = tid; i < 6144; i += NTHR) {
        const int px = i & 127;
        const int s  = i >> 7;           // 0..47 = ci*3+ky
        const int ci = s / 3;
        const int ky = s - ci * 3;
        const float* xr = &xt[ci * 396 + ky * 132 + px];
        unsigned short* dst = (unsigned short*)(Ab + px * 336) + (ci * 9 + ky * 3);
        dst[0] = f2bf(xr[0]); dst[1] = f2bf(xr[1]); dst[2] = f2bf(xr[2]);
    }
    for (int i = tid; i < 1536; i += NTHR) {      // zero A pad k 144..167
        const int px = i / 12, j = i - px * 12;
        *(unsigned int*)(Ab + px * 336 + 288 + j * 4) = 0u;
    }

    // ---- phase 5: per-expert implicit GEMM (barriers unconditional) ----
    const int lane = tid & 63;
    const int wave = tid >> 6;           // 0..7
    const int quad = lane >> 4;          // 0..3
    const int lq   = lane & 15;

    for (int e = 0; e < 16; ++e) {
        const int n_e = cnt[e];
        __syncthreads();                 // prior iteration's Bt reads complete
        if (n_e) {
            const float* we = ew + e * 9216;
            for (int i = tid; i < 4608; i += NTHR) {
                const float2 v = *(const float2*)(we + i * 2);
                const int cout = i / 72;
                const int k    = i * 2 - cout * 144;
                const unsigned int pk = (unsigned int)f2bf(v.x) | ((unsigned int)f2bf(v.y) << 16);
                *(unsigned int*)(Btb + cout * 336 + k * 2) = pk;
            }
            for (int i = tid; i < 768; i += NTHR) {   // zero Bt pad k 144..167
                const int cout = i / 12, j = i - cout * 12;
                *(unsigned int*)(Btb + cout * 336 + 288 + j * 4) = 0u;
            }
        }
        __syncthreads();                 // Bt staged
        if (n_e) {
            const int nb    = basep[e];
            const int units = ((n_e + 15) >> 4) * 4;
            for (int u = wave; u < units; u += 8) {
                const int tile  = u >> 2;
                const int nf    = u & 3;
                const int mbase = tile * 16;
                const int mi    = mbase + lq;
                const int apix  = list_pix[nb + (mi < n_e ? mi : n_e - 1)];  // clamped, in-bounds
                const char* arow = Ab  + apix * 336 + quad * 16;
                const char* brow = Btb + (lq + 16 * nf) * 336 + quad * 16;
                f32x4 acc = {0.f, 0.f, 0.f, 0.f};
                #pragma unroll
                for (int ks = 0; ks < 5; ++ks) {
                    const bf16x8 av = *(const bf16x8*)(arow + ks * 64);
                    const bf16x8 bv = *(const bf16x8*)(brow + ks * 64);
                    acc = __builtin_amdgcn_mfma_f32_16x16x32_bf16(av, bv, acc, 0, 0, 0);
                }
                const int   n    = lq + 16 * nf;      // C/D: col = lane&15
                const float bias = ebs[e * 64 + n];
                #pragma unroll
                for (int r = 0; r < 4; ++r) {         // C/D: row = quad*4 + r
                    const int m = mbase + quad * 4 + r;
                    if (m < n_e) {
                        const int   pr = list_pix[nb + m];
                        const float wr = list_w[nb + m];
                        outt[pr * 65 + n] += wr * (acc[r] + bias);
                    }
                }
            }
        }
    }
    __syncthreads();

    // ---- phase 6: writeout (LDS 2-way free, global coalesced) ----
    for (int i = tid; i < 8192; i += NTHR) {
        const int c = i >> 7, px = i & 127;
        out[((b * 64 + c) * 128 + row) * 128 + px] = outt[px * 65 + c];
    }
}

extern "C" void kernel_launch(void* const* d_in, const int* in_sizes, int n_in,
                              void* d_out, int out_size, void* d_ws, size_t ws_size,
                              hipStream_t stream) {
    const float* x  = (const float*)d_in[0];
    const float* gw = (const float*)d_in[1];
    const float* gb = (const float*)d_in[2];
    const float* ew = (const float*)d_in[3];
    const float* eb = (const float*)d_in[4];
    float* out        = (float*)d_out;
    float* logits_out = out + 8 * 64 * 128 * 128;

    (void)hipFuncSetAttribute((const void*)moe_mfma3_kernel,
                              hipFuncAttributeMaxDynamicSharedMemorySize,
                              SMEM_B);
    moe_mfma3_kernel<<<dim3(1024), dim3(NTHR), SMEM_B, stream>>>(x, gw, gb, ew, eb, out, logits_out);
}

// Round 4
// 200.853 us; speedup vs baseline: 1.6277x; 1.3753x over previous
//
#include <hip/hip_runtime.h>
#include <cmath>

// B=8, Cin=16, H=W=128, Cout=64, E=16, K=2
#define NTHR 512

typedef __attribute__((ext_vector_type(8))) short bf16x8;   // MFMA A/B frag (4 VGPRs)
typedef __attribute__((ext_vector_type(4))) float f32x4;    // MFMA C/D frag

// LDS layout (bytes), total 78720 (<80 KiB -> 2 blocks/CU):
//   A    : [0, 43008)        im2col bf16 [128 px][336 B] (k 0..143 data, 144..167 zero)
//   outt : [43008, 76288)    fp32 [128 px][65]
//   lpix : [76288, 77312)    int[256]
//   lw   : [77312, 78336)    float[256]
//   cnt  : [78336, 78400)    int[16]
//   base : [78400, 78464)    int[16]
//   mask : [78464, 78720)    u64[16][2]
#define OFF_OUTT 43008
#define OFF_LPIX 76288
#define OFF_LW   77312
#define OFF_CNT  78336
#define OFF_BASE 78400
#define OFF_MASK 78464
#define SMEM_B   78720

static __device__ __forceinline__ unsigned short f2bf(float f) {
    union { float f; unsigned int u; } v; v.f = f;
    unsigned int r = v.u + 0x7FFFu + ((v.u >> 16) & 1u);   // round-to-nearest-even
    return (unsigned short)(r >> 16);
}

// ---- prep: ew [16][64][144] fp32 -> wb [e*64+n][160] bf16 (B-frag row layout) ----
__global__ __launch_bounds__(256) void prep_w_kernel(const float* __restrict__ ew,
                                                     unsigned short* __restrict__ wb) {
    const int chunk = blockIdx.x * 256 + threadIdx.x;   // one 8-bf16 chunk
    if (chunk >= 20480) return;                         // 1024 rows * 20 chunks
    const int rowid = chunk / 20;                       // e*64 + cout
    const int kc    = chunk - rowid * 20;
    unsigned int d0 = 0, d1 = 0, d2 = 0, d3 = 0;
    if (kc < 18) {                                      // 144 = 18*8, chunks 18..19 are zero pad
        const float* s = ew + rowid * 144 + kc * 8;
        d0 = (unsigned int)f2bf(s[0]) | ((unsigned int)f2bf(s[1]) << 16);
        d1 = (unsigned int)f2bf(s[2]) | ((unsigned int)f2bf(s[3]) << 16);
        d2 = (unsigned int)f2bf(s[4]) | ((unsigned int)f2bf(s[5]) << 16);
        d3 = (unsigned int)f2bf(s[6]) | ((unsigned int)f2bf(s[7]) << 16);
    }
    uint4* dst = (uint4*)(wb + rowid * 160 + kc * 8);   // 16B aligned
    *dst = make_uint4(d0, d1, d2, d3);
}

__global__ __launch_bounds__(512, 4) void moe_mfma4_kernel(
    const float* __restrict__ x,              // [8][16][128][128]
    const float* __restrict__ gw,             // [16][16]
    const float* __restrict__ gb,             // [16]
    const unsigned short* __restrict__ wb,    // [1024][160] bf16 (prepped)
    const float* __restrict__ eb,             // [16][64]
    float* __restrict__ out,                  // [8][64][128][128]
    float* __restrict__ logits_out)           // [8][16][128][128]
{
    extern __shared__ char lds[];
    char*  Ab       = lds;
    float* outt     = (float*)(lds + OFF_OUTT);
    int*   list_pix = (int*)(lds + OFF_LPIX);
    float* list_w   = (float*)(lds + OFF_LW);
    int*   cnt      = (int*)(lds + OFF_CNT);
    int*   basep    = (int*)(lds + OFF_BASE);
    unsigned long long* emask = (unsigned long long*)(lds + OFF_MASK);

    const int tid = threadIdx.x;
    const int b   = blockIdx.x >> 7;      // 8 batches
    const int row = blockIdx.x & 127;     // 128 rows

    // ---- phase 1: zero outt + masks ----
    for (int i = tid; i < 2080; i += NTHR)
        ((float4*)outt)[i] = make_float4(0.f, 0.f, 0.f, 0.f);
    if (tid < 32) emask[tid] = 0ull;
    __syncthreads();

    // ---- phase 2: gate (fp32, exact; x read direct from global, coalesced) ----
    int i0 = 0, i1 = 0; float w0 = 0.f, w1 = 0.f;
    if (tid < 128) {
        const float* xp = x + (b * 16) * 16384 + row * 128 + tid;
        float xv[16];
        #pragma unroll
        for (int ci = 0; ci < 16; ++ci) xv[ci] = xp[ci * 16384];
        float l[16];
        #pragma unroll
        for (int o = 0; o < 16; ++o) {
            float acc = gb[o];
            #pragma unroll
            for (int i = 0; i < 16; ++i) acc += gw[o * 16 + i] * xv[i];
            l[o] = acc;
        }
        const int rbase = ((b * 16) * 128 + row) * 128 + tid;
        #pragma unroll
        for (int o = 0; o < 16; ++o) logits_out[rbase + o * 16384] = l[o];

        float m = l[0];
        #pragma unroll
        for (int o = 1; o < 16; ++o) m = fmaxf(m, l[o]);
        float p0 = expf(l[0] - m), p1 = -1.f;
        #pragma unroll
        for (int o = 1; o < 16; ++o) {
            float pv = expf(l[o] - m);
            if (pv > p0)      { p1 = p0; i1 = i0; p0 = pv; i0 = o; }
            else if (pv > p1) { p1 = pv; i1 = o; }
        }
        const float ws = p0 + p1;
        w0 = p0 / ws; w1 = p1 / ws;
        const unsigned long long bit = 1ull << (tid & 63);
        const int half = tid >> 6;
        atomicOr(&emask[i0 * 2 + half], bit);
        atomicOr(&emask[i1 * 2 + half], bit);
    }
    __syncthreads();

    // ---- phase 3: counts + bases (deterministic) ----
    if (tid == 0) {
        int run = 0;
        for (int e = 0; e < 16; ++e) {
            int c = __popcll(emask[e * 2]) + __popcll(emask[e * 2 + 1]);
            basep[e] = run; cnt[e] = c; run += c;
        }
    }
    __syncthreads();

    // ---- phase 4: deterministic list fill + im2col A from global ----
    if (tid < 128) {
        #pragma unroll
        for (int s = 0; s < 2; ++s) {
            const int   e  = s ? i1 : i0;
            const float wv = s ? w1 : w0;
            const unsigned long long lo = emask[e * 2], hi = emask[e * 2 + 1];
            int pos;
            if (tid < 64) pos = __popcll(lo & ((1ull << tid) - 1ull));
            else          pos = __popcll(lo) + __popcll(hi & ((1ull << (tid - 64)) - 1ull));
            const int slot = basep[e] + pos;
            list_pix[slot] = tid;
            list_w[slot]   = wv;
        }
    }
    {   // A[px][k], k = ci*9+ky*3+kx; px fixed per thread, s = s0+4j (wave-uniform)
        const int px = tid & 127;
        const int s0 = tid >> 7;
        #pragma unroll
        for (int j = 0; j < 12; ++j) {
            const int s  = s0 + 4 * j;
            const int ci = s / 3;
            const int ky = s - ci * 3;
            const int gr = row - 1 + ky;
            unsigned short v0 = 0, v1 = 0, v2 = 0;
            if (gr >= 0 && gr < 128) {
                const float* xr = x + ((b * 16 + ci) * 128 + gr) * 128;
                if (px > 0)   v0 = f2bf(xr[px - 1]);
                v1 = f2bf(xr[px]);
                if (px < 127) v2 = f2bf(xr[px + 1]);
            }
            unsigned short* dst = (unsigned short*)(Ab + px * 336) + (ci * 9 + ky * 3);
            dst[0] = v0; dst[1] = v1; dst[2] = v2;
        }
    }
    for (int i = tid; i < 1536; i += NTHR) {      // zero A pad k 144..167
        const int p2 = i / 12, jj = i - p2 * 12;
        *(unsigned int*)(Ab + p2 * 336 + 288 + jj * 4) = 0u;
    }
    __syncthreads();

    // ---- phase 5: barrier-free per-expert implicit GEMM ----
    const int lane = tid & 63;
    const int wave = tid >> 6;           // 0..7
    const int quad = lane >> 4;          // 0..3
    const int lq   = lane & 15;
    const int nf   = wave & 3;           // loop-invariant n-fragment per wave
    const int n    = lq + 16 * nf;       // C/D col (lane&15) + frag offset

    for (int e = 0; e < 16; ++e) {
        const int n_e   = cnt[e];
        const int units = ((n_e + 15) >> 4) << 2;
        if (wave >= units) continue;     // wave-uniform

        // B-frags: registers, straight from L2 (prepped bf16 layout)
        const unsigned short* wrow = wb + (e * 64 + n) * 160;
        bf16x8 bfr[5];
        #pragma unroll
        for (int ks = 0; ks < 5; ++ks)
            bfr[ks] = *(const bf16x8*)(wrow + quad * 8 + ks * 32);
        const float bias = eb[e * 64 + n];
        const int   nb   = basep[e];

        for (int u = wave; u < units; u += 8) {   // u&3 == nf always
            const int tile  = u >> 2;
            const int mbase = tile << 4;
            const int mi    = mbase + lq;
            const int apix  = list_pix[nb + (mi < n_e ? mi : n_e - 1)];
            const char* arow = Ab + apix * 336 + quad * 16;
            f32x4 acc = {0.f, 0.f, 0.f, 0.f};
            #pragma unroll
            for (int ks = 0; ks < 5; ++ks) {
                const bf16x8 av = *(const bf16x8*)(arow + ks * 64);
                acc = __builtin_amdgcn_mfma_f32_16x16x32_bf16(av, bfr[ks], acc, 0, 0, 0);
            }
            #pragma unroll
            for (int r = 0; r < 4; ++r) {         // C/D row = quad*4 + r
                const int m = mbase + quad * 4 + r;
                if (m < n_e) {
                    const int   pr = list_pix[nb + m];
                    const float wr = list_w[nb + m];
                    atomicAdd(&outt[pr * 65 + n], wr * acc[r] + wr * bias);
                }
            }
        }
    }
    __syncthreads();

    // ---- phase 6: writeout (LDS stride 65 conflict-free, global coalesced) ----
    for (int i = tid; i < 8192; i += NTHR) {
        const int c = i >> 7, px = i & 127;
        out[((b * 64 + c) * 128 + row) * 128 + px] = outt[px * 65 + c];
    }
}

extern "C" void kernel_launch(void* const* d_in, const int* in_sizes, int n_in,
                              void* d_out, int out_size, void* d_ws, size_t ws_size,
                              hipStream_t stream) {
    const float* x  = (const float*)d_in[0];
    const float* gw = (const float*)d_in[1];
    const float* gb = (const float*)d_in[2];
    const float* ew = (const float*)d_in[3];
    const float* eb = (const float*)d_in[4];
    float* out        = (float*)d_out;
    float* logits_out = out + 8 * 64 * 128 * 128;
    unsigned short* wb = (unsigned short*)d_ws;      // 1024*160*2 = 327,680 B

    prep_w_kernel<<<dim3(80), dim3(256), 0, stream>>>(ew, wb);

    (void)hipFuncSetAttribute((const void*)moe_mfma4_kernel,
                              hipFuncAttributeMaxDynamicSharedMemorySize,
                              SMEM_B);
    moe_mfma4_kernel<<<dim3(1024), dim3(NTHR), SMEM_B, stream>>>(
        x, gw, gb, wb, eb, out, logits_out);
}

// Round 5
// 198.183 us; speedup vs baseline: 1.6496x; 1.0135x over previous
//
#include <hip/hip_runtime.h>
#include <cmath>

// B=8, Cin=16, H=W=128, Cout=64, E=16, K=2
#define NTHR 512

typedef __attribute__((ext_vector_type(8))) short bf16x8;   // MFMA A/B frag (4 VGPRs)
typedef __attribute__((ext_vector_type(4))) float f32x4;    // MFMA C/D frag

// LDS layout (bytes), total 78720 (2 blocks/CU):
//   A    : [0, 43008)        im2col bf16 [128 px][336 B] (k 0..143 data, 144..167 zero)
//   outt : [43008, 76288)    fp32 [128 px][65]
//   lpix : [76288, 77312)    int[256]
//   lw   : [77312, 78336)    float[256]
//   cnt  : [78336, 78400)    int[16]
//   base : [78400, 78464)    int[16]
//   mask : [78464, 78720)    u64[16][2]
#define OFF_OUTT 43008
#define OFF_LPIX 76288
#define OFF_LW   77312
#define OFF_CNT  78336
#define OFF_BASE 78400
#define OFF_MASK 78464
#define SMEM_B   78720

static __device__ __forceinline__ unsigned short f2bf(float f) {
    union { float f; unsigned int u; } v; v.f = f;
    unsigned int r = v.u + 0x7FFFu + ((v.u >> 16) & 1u);   // round-to-nearest-even
    return (unsigned short)(r >> 16);
}

__global__ __launch_bounds__(512, 4) void moe_mfma5_kernel(
    const float* __restrict__ x,      // [8][16][128][128]
    const float* __restrict__ gw,     // [16][16]
    const float* __restrict__ gb,     // [16]
    const float* __restrict__ ew,     // [16][64][16][3][3] = [16][64][144]
    const float* __restrict__ eb,     // [16][64]
    float* __restrict__ out,          // [8][64][128][128]
    float* __restrict__ logits_out)   // [8][16][128][128]
{
    extern __shared__ char lds[];
    char*  Ab       = lds;
    float* outt     = (float*)(lds + OFF_OUTT);
    int*   list_pix = (int*)(lds + OFF_LPIX);
    float* list_w   = (float*)(lds + OFF_LW);
    int*   cnt      = (int*)(lds + OFF_CNT);
    int*   basep    = (int*)(lds + OFF_BASE);
    unsigned long long* emask = (unsigned long long*)(lds + OFF_MASK);

    const int tid = threadIdx.x;
    const int b   = blockIdx.x >> 7;      // 8 batches
    const int row = blockIdx.x & 127;     // 128 rows

    const int lane = tid & 63;
    const int wave = tid >> 6;            // 0..7
    const int quad = lane >> 4;           // 0..3
    const int lq   = lane & 15;
    const int nf   = wave & 3;            // loop-invariant n-fragment per wave
    const int n    = lq + 16 * nf;        // this lane's cout

    // per-lane B source pointer: ew[e][n][ks*32 + quad*8 .. +7], quad*8 baked in
    const float* wlane = ew + n * 144 + quad * 8;

    // ---- phase 1: zero outt + masks ----
    for (int i = tid; i < 2080; i += NTHR)
        ((float4*)outt)[i] = make_float4(0.f, 0.f, 0.f, 0.f);
    if (tid < 32) emask[tid] = 0ull;
    __syncthreads();

    // ---- phase 2: gate (fp32, exact) ----
    int i0 = 0, i1 = 0; float w0 = 0.f, w1 = 0.f;
    if (tid < 128) {
        const float* xp = x + (b * 16) * 16384 + row * 128 + tid;
        float xv[16];
        #pragma unroll
        for (int ci = 0; ci < 16; ++ci) xv[ci] = xp[ci * 16384];   // 16 batched loads
        float l[16];
        #pragma unroll
        for (int o = 0; o < 16; ++o) {
            float acc = gb[o];
            #pragma unroll
            for (int i = 0; i < 16; ++i) acc += gw[o * 16 + i] * xv[i];
            l[o] = acc;
        }
        const int rbase = ((b * 16) * 128 + row) * 128 + tid;
        #pragma unroll
        for (int o = 0; o < 16; ++o) logits_out[rbase + o * 16384] = l[o];

        float m = l[0];
        #pragma unroll
        for (int o = 1; o < 16; ++o) m = fmaxf(m, l[o]);
        float p0 = expf(l[0] - m), p1 = -1.f;
        #pragma unroll
        for (int o = 1; o < 16; ++o) {
            float pv = expf(l[o] - m);
            if (pv > p0)      { p1 = p0; i1 = i0; p0 = pv; i0 = o; }
            else if (pv > p1) { p1 = pv; i1 = o; }
        }
        const float ws = p0 + p1;
        w0 = p0 / ws; w1 = p1 / ws;
        const unsigned long long bit = 1ull << (tid & 63);
        const int half = tid >> 6;
        atomicOr(&emask[i0 * 2 + half], bit);
        atomicOr(&emask[i1 * 2 + half], bit);
    }
    __syncthreads();

    // ---- phase 3: counts + bases (deterministic) ----
    if (tid == 0) {
        int run = 0;
        for (int e = 0; e < 16; ++e) {
            int c = __popcll(emask[e * 2]) + __popcll(emask[e * 2 + 1]);
            basep[e] = run; cnt[e] = c; run += c;
        }
    }

    // prefetch expert 0's B block + bias (pure global, overlaps phase 4)
    float4 nx[10]; float nxb;
    {
        const float* p = wlane;
        #pragma unroll
        for (int ks = 0; ks < 4; ++ks) {
            nx[2 * ks]     = *(const float4*)(p + ks * 32);
            nx[2 * ks + 1] = *(const float4*)(p + ks * 32 + 4);
        }
        if (quad < 2) { nx[8] = *(const float4*)(p + 128); nx[9] = *(const float4*)(p + 132); }
        else          { nx[8] = make_float4(0,0,0,0);      nx[9] = make_float4(0,0,0,0); }
        nxb = eb[n];
    }
    __syncthreads();

    // ---- phase 4: deterministic list fill + im2col A (batched loads) ----
    if (tid < 128) {
        #pragma unroll
        for (int s = 0; s < 2; ++s) {
            const int   e  = s ? i1 : i0;
            const float wv = s ? w1 : w0;
            const unsigned long long lo = emask[e * 2], hi = emask[e * 2 + 1];
            int pos;
            if (tid < 64) pos = __popcll(lo & ((1ull << tid) - 1ull));
            else          pos = __popcll(lo) + __popcll(hi & ((1ull << (tid - 64)) - 1ull));
            const int slot = basep[e] + pos;
            list_pix[slot] = tid;
            list_w[slot]   = wv;
        }
    }
    {   // im2col: stage all 36 floats first (one waitcnt batch), then convert+store
        const int px = tid & 127;
        const int s0 = tid >> 7;
        float xv[36];
        #pragma unroll
        for (int j = 0; j < 12; ++j) {
            const int s  = s0 + 4 * j;
            const int ci = s / 3;
            const int ky = s - ci * 3;
            int gr = row - 1 + ky;
            gr = gr < 0 ? 0 : (gr > 127 ? 127 : gr);           // clamp, mask later
            const float* xr = x + ((b * 16 + ci) * 128 + gr) * 128;
            xv[3 * j + 0] = (px > 0)   ? xr[px - 1] : 0.f;
            xv[3 * j + 1] = xr[px];
            xv[3 * j + 2] = (px < 127) ? xr[px + 1] : 0.f;
        }
        #pragma unroll
        for (int j = 0; j < 12; ++j) {
            const int s  = s0 + 4 * j;
            const int ci = s / 3;
            const int ky = s - ci * 3;
            const int gr = row - 1 + ky;
            const bool ok = (gr >= 0) && (gr < 128);
            unsigned short* dst = (unsigned short*)(Ab + px * 336) + (ci * 9 + ky * 3);
            dst[0] = ok ? f2bf(xv[3 * j + 0]) : (unsigned short)0;
            dst[1] = ok ? f2bf(xv[3 * j + 1]) : (unsigned short)0;
            dst[2] = ok ? f2bf(xv[3 * j + 2]) : (unsigned short)0;
        }
    }
    for (int i = tid; i < 1536; i += NTHR) {      // zero A pad k 144..167
        const int p2 = i / 12, jj = i - p2 * 12;
        *(unsigned int*)(Ab + p2 * 336 + 288 + jj * 4) = 0u;
    }
    __syncthreads();

    // ---- phase 5: software-pipelined per-expert implicit GEMM ----
    for (int e = 0; e < 16; ++e) {
        // convert prefetched fp32 -> bf16 B-frags (waits on nx loads)
        bf16x8 bfr[5];
        #pragma unroll
        for (int ks = 0; ks < 5; ++ks) {
            const float4 a = nx[2 * ks], c = nx[2 * ks + 1];
            bf16x8 v;
            v[0] = (short)f2bf(a.x); v[1] = (short)f2bf(a.y);
            v[2] = (short)f2bf(a.z); v[3] = (short)f2bf(a.w);
            v[4] = (short)f2bf(c.x); v[5] = (short)f2bf(c.y);
            v[6] = (short)f2bf(c.z); v[7] = (short)f2bf(c.w);
            bfr[ks] = v;
        }
        const float bias = nxb;

        // prefetch next expert (latency hidden by this expert's compute)
        if (e < 15) {
            const float* p = wlane + (e + 1) * 9216;
            #pragma unroll
            for (int ks = 0; ks < 4; ++ks) {
                nx[2 * ks]     = *(const float4*)(p + ks * 32);
                nx[2 * ks + 1] = *(const float4*)(p + ks * 32 + 4);
            }
            if (quad < 2) { nx[8] = *(const float4*)(p + 128); nx[9] = *(const float4*)(p + 132); }
            nxb = eb[(e + 1) * 64 + n];
        }

        const int n_e   = cnt[e];
        const int units = ((n_e + 15) >> 4) << 2;
        const int nb    = basep[e];
        for (int u = wave; u < units; u += 8) {   // u&3 == nf always
            const int mbase = (u >> 2) << 4;
            const int mi    = mbase + lq;
            const int apix  = list_pix[nb + (mi < n_e ? mi : n_e - 1)];
            // hoist epilogue pairs (independent of MFMA chain)
            int prr[4]; float wrr[4];
            #pragma unroll
            for (int r = 0; r < 4; ++r) {
                int m = mbase + quad * 4 + r;
                m = m < n_e ? m : n_e - 1;
                prr[r] = list_pix[nb + m];
                wrr[r] = list_w[nb + m];
            }
            const char* arow = Ab + apix * 336 + quad * 16;
            bf16x8 av[5];
            #pragma unroll
            for (int ks = 0; ks < 5; ++ks) av[ks] = *(const bf16x8*)(arow + ks * 64);
            f32x4 acc = {0.f, 0.f, 0.f, 0.f};
            #pragma unroll
            for (int ks = 0; ks < 5; ++ks)
                acc = __builtin_amdgcn_mfma_f32_16x16x32_bf16(av[ks], bfr[ks], acc, 0, 0, 0);
            #pragma unroll
            for (int r = 0; r < 4; ++r) {         // C/D row = quad*4 + r
                if (mbase + quad * 4 + r < n_e)
                    atomicAdd(&outt[prr[r] * 65 + n], wrr[r] * (acc[r] + bias));
            }
        }
    }
    __syncthreads();

    // ---- phase 6: writeout, unrolled x4 (batched ds_reads) ----
    #pragma unroll
    for (int i = 0; i < 8192; i += 2048) {
        float v[4];
        #pragma unroll
        for (int j = 0; j < 4; ++j) {
            const int ii = i + j * 512 + tid;
            v[j] = outt[(ii & 127) * 65 + (ii >> 7)];
        }
        #pragma unroll
        for (int j = 0; j < 4; ++j) {
            const int ii = i + j * 512 + tid;
            out[((b * 64 + (ii >> 7)) * 128 + row) * 128 + (ii & 127)] = v[j];
        }
    }
}

extern "C" void kernel_launch(void* const* d_in, const int* in_sizes, int n_in,
                              void* d_out, int out_size, void* d_ws, size_t ws_size,
                              hipStream_t stream) {
    const float* x  = (const float*)d_in[0];
    const float* gw = (const float*)d_in[1];
    const float* gb = (const float*)d_in[2];
    const float* ew = (const float*)d_in[3];
    const float* eb = (const float*)d_in[4];
    float* out        = (float*)d_out;
    float* logits_out = out + 8 * 64 * 128 * 128;

    (void)hipFuncSetAttribute((const void*)moe_mfma5_kernel,
                              hipFuncAttributeMaxDynamicSharedMemorySize,
                              SMEM_B);
    moe_mfma5_kernel<<<dim3(1024), dim3(NTHR), SMEM_B, stream>>>(
        x, gw, gb, ew, eb, out, logits_out);
}